// Round 1
// baseline (5551.814 us; speedup 1.0000x reference)
//
#include <hip/hip_runtime.h>

// SOHMM forward, MI355X gfx950.
// Persistent kernel: 256 blocks (j in 0..127  x  i-half in 0..1) x 256 threads (4 waves).
// 129 custom grid barriers (phase0 + 127 steps + final).
// Per step, block (j, ih):
//   M[b]   = max over all blocks' pmax            (global per-b max, matches reference)
//   E[k,b] = exp(y_prev[j,k,b] - M[b]) -> bf16 in LDS transposed as ET[b][k]
//   acc    = alpha[i,j,:] @ E   via mfma_f32_16x16x32_bf16 (A-frags register-resident)
//   y_new  = log(acc + 1e-12) + M[b] + beta[j, ids[b, S-1-s]]  -> ys[s] (d_out) + pmax

#define Hd 128
#define Bd 64
#define Sd 128
#define Vd 32000
#define HBc (Hd * Bd)          // 8192
#define HHBc (Hd * Hd * Bd)    // 1048576
#define NBLK 256
#define EPSF 1e-12f

typedef __attribute__((ext_vector_type(4))) float f32x4;
typedef __attribute__((ext_vector_type(8))) short s16x8;
typedef __attribute__((ext_vector_type(4))) short s16x4;

__device__ __forceinline__ short f2bf(float f) {
  unsigned u = __builtin_bit_cast(unsigned, f);
  unsigned r = (u + 0x7fffu + ((u >> 16) & 1u)) >> 16;
  return (short)(r & 0xffffu);
}

__device__ __forceinline__ void grid_barrier(unsigned* bar) {
  __syncthreads();
  if (threadIdx.x == 0) {
    __threadfence();
    unsigned g = __hip_atomic_load(&bar[1], __ATOMIC_RELAXED, __HIP_MEMORY_SCOPE_AGENT);
    unsigned a = __hip_atomic_fetch_add(&bar[0], 1u, __ATOMIC_ACQ_REL, __HIP_MEMORY_SCOPE_AGENT);
    if (a == (unsigned)(NBLK - 1)) {
      __hip_atomic_store(&bar[0], 0u, __ATOMIC_RELAXED, __HIP_MEMORY_SCOPE_AGENT);
      __hip_atomic_store(&bar[1], g + 1u, __ATOMIC_RELEASE, __HIP_MEMORY_SCOPE_AGENT);
    } else {
      unsigned spins = 0;
      while (__hip_atomic_load(&bar[1], __ATOMIC_ACQUIRE, __HIP_MEMORY_SCOPE_AGENT) == g) {
        __builtin_amdgcn_s_sleep(2);
        if (++spins > (1u << 24)) break;  // bail instead of hard-hang
      }
    }
    __threadfence();
  }
  __syncthreads();
}

__global__ __launch_bounds__(256) void sohmm_persistent(
    const int* __restrict__ ids, const float* __restrict__ alpha,
    const float* __restrict__ beta, const float* __restrict__ gamma,
    float* __restrict__ out, float* __restrict__ wsf) {
  unsigned* bar = (unsigned*)wsf;
  float* pmax = wsf + 16;             // [NBLK][64]
  float* gpart = pmax + NBLK * Bd;    // [NBLK][64]
  float* gstat = gpart + NBLK * Bd;   // [2] : gamma max, gamma sum-exp

  const int tid = threadIdx.x;
  const int bid = blockIdx.x;
  const int j = bid >> 1;
  const int ih = bid & 1;
  const int lane = tid & 63;
  const int w = tid >> 6;      // wave 0..3
  const int l15 = lane & 15;
  const int g4 = lane >> 4;    // 0..3
  const int ibase = ih * 64 + w * 16 + g4 * 4;  // this lane's first output row

  __shared__ __align__(16) short ET[64][132];   // E^T[b][k] bf16, stride 264 B
  __shared__ float Mb[64];
  __shared__ float ipb[64];
  __shared__ float red4[4][64];
  __shared__ float wred[4][64];
  __shared__ float gex[128];

  // ---- A fragments: alpha[i, j, k] rows, loaded once, kept in VGPRs ----
  s16x8 afrag[4];
  {
    const int i = ih * 64 + w * 16 + l15;
    const float* ap = alpha + ((size_t)i * Hd + j) * Hd;
#pragma unroll
    for (int kc = 0; kc < 4; ++kc) {
      const int k = kc * 32 + g4 * 8;
      f32x4 a0 = *(const f32x4*)(ap + k);
      f32x4 a1 = *(const f32x4*)(ap + k + 4);
      s16x8 f;
      f[0] = f2bf(a0[0]); f[1] = f2bf(a0[1]); f[2] = f2bf(a0[2]); f[3] = f2bf(a0[3]);
      f[4] = f2bf(a1[0]); f[5] = f2bf(a1[1]); f[6] = f2bf(a1[2]); f[7] = f2bf(a1[3]);
      afrag[kc] = f;
    }
  }

  // ---- phase 0: y0 = broadcast beta[j, ids[b, S-1]], pmax, gamma stats ----
  if (tid < Bd) {
    int id = ids[tid * Sd + (Sd - 1)];
    float v = beta[(size_t)j * Vd + id];
    ipb[tid] = v;
    pmax[bid * Bd + tid] = v;  // max over i of a value constant in i
  }
  __syncthreads();
  {
    const int b = tid & 63;
    const float v = ipb[b];
    const int i0 = ih * 64 + (tid >> 6);
#pragma unroll
    for (int ii = 0; ii < 64; ii += 4)
      out[(size_t)(i0 + ii) * HBc + j * Bd + b] = v;
  }
  if (bid == 0) {
    // gamma softmax stats over all 16384 entries
    float m = -3.4e38f;
    for (int q = tid; q < Hd * Hd; q += 256) m = fmaxf(m, gamma[q]);
#pragma unroll
    for (int o = 32; o >= 1; o >>= 1) m = fmaxf(m, __shfl_xor(m, o, 64));
    if (lane == 0) red4[0][w] = m;
    __syncthreads();
    m = fmaxf(fmaxf(red4[0][0], red4[0][1]), fmaxf(red4[0][2], red4[0][3]));
    float ssum = 0.f;
    for (int q = tid; q < Hd * Hd; q += 256) ssum += __expf(gamma[q] - m);
#pragma unroll
    for (int o = 32; o >= 1; o >>= 1) ssum += __shfl_xor(ssum, o, 64);
    if (lane == 0) red4[1][w] = ssum;
    __syncthreads();
    if (tid == 0) {
      gstat[0] = m;
      gstat[1] = red4[1][0] + red4[1][1] + red4[1][2] + red4[1][3];
    }
  }
  grid_barrier(bar);

  // ---- main scan: s = 1 .. 127 ----
  float val[4][4];
#pragma unroll 1
  for (int s = 1; s < Sd; ++s) {
    // 1) global per-b max from all blocks' pmax
    {
      const int b = tid & 63, qg = tid >> 6;
      float m = -3.4e38f;
      for (int q = qg; q < NBLK; q += 4) m = fmaxf(m, pmax[q * Bd + b]);
      red4[qg][b] = m;
    }
    __syncthreads();
    if (tid < 64) {
      Mb[tid] = fmaxf(fmaxf(red4[0][tid], red4[1][tid]),
                      fmaxf(red4[2][tid], red4[3][tid]));
      int id = ids[tid * Sd + (Sd - 1 - s)];
      ipb[tid] = beta[(size_t)j * Vd + id];
    }
    __syncthreads();

    // 2) stage E^T into LDS: ET[b][k] = bf16(exp(y_prev[j,k,b] - M[b]))
    {
      const int b = tid & 63;
      const int kq = (tid >> 6) * 4;
      const float M = Mb[b];
      const float* yp = out + (size_t)(s - 1) * HHBc + (size_t)j * HBc + b;
#pragma unroll
      for (int m0 = 0; m0 < 128; m0 += 16) {
        const int k0 = m0 + kq;
        s16x4 sv;
#pragma unroll
        for (int e = 0; e < 4; ++e) {
          float y = yp[(size_t)(k0 + e) * Bd];
          sv[e] = f2bf(__expf(y - M));
        }
        *(s16x4*)&ET[b][k0] = sv;
      }
    }
    __syncthreads();

    // 3) MFMA: acc[i16, b16] += A[i,k] * E[k,b]
    f32x4 acc[4];
#pragma unroll
    for (int bt = 0; bt < 4; ++bt) acc[bt] = (f32x4){0.f, 0.f, 0.f, 0.f};
#pragma unroll
    for (int kc = 0; kc < 4; ++kc) {
#pragma unroll
      for (int bt = 0; bt < 4; ++bt) {
        const int bb = bt * 16 + l15;
        const int kk = kc * 32 + g4 * 8;
        union { s16x4 h[2]; s16x8 v; } u;
        u.h[0] = *(const s16x4*)&ET[bb][kk];
        u.h[1] = *(const s16x4*)&ET[bb][kk + 4];
        acc[bt] = __builtin_amdgcn_mfma_f32_16x16x32_bf16(afrag[kc], u.v, acc[bt], 0, 0, 0);
      }
    }

    // 4) epilogue: val = log(acc+eps) + M + ip ; store ys[s]; per-b block max
    float* ycur = out + (size_t)s * HHBc;
    float lmax[4];
#pragma unroll
    for (int bt = 0; bt < 4; ++bt) {
      const int b = bt * 16 + l15;
      const float add = Mb[b] + ipb[b];
      float mx = -3.4e38f;
#pragma unroll
      for (int r = 0; r < 4; ++r) {
        float vv = __logf(acc[bt][r] + EPSF) + add;
        val[bt][r] = vv;
        ycur[(size_t)(ibase + r) * HBc + j * Bd + b] = vv;
        mx = fmaxf(mx, vv);
      }
      mx = fmaxf(mx, __shfl_xor(mx, 16, 64));
      mx = fmaxf(mx, __shfl_xor(mx, 32, 64));
      lmax[bt] = mx;
    }
    if (lane < 16) {
#pragma unroll
      for (int bt = 0; bt < 4; ++bt) wred[w][bt * 16 + lane] = lmax[bt];
    }
    __syncthreads();
    if (tid < 64) {
      float m = fmaxf(fmaxf(wred[0][tid], wred[1][tid]),
                      fmaxf(wred[2][tid], wred[3][tid]));
      pmax[bid * Bd + tid] = m;
    }
    grid_barrier(bar);
  }

  // ---- final: y_final[b] = log(sum_ij gamma_exp * exp(y_last - M) + eps) + M ----
  {
    const int b = tid & 63, qg = tid >> 6;
    float m = -3.4e38f;
    for (int q = qg; q < NBLK; q += 4) m = fmaxf(m, pmax[q * Bd + b]);
    red4[qg][b] = m;
  }
  __syncthreads();
  if (tid < 64)
    Mb[tid] = fmaxf(fmaxf(red4[0][tid], red4[1][tid]),
                    fmaxf(red4[2][tid], red4[3][tid]));
  if (tid < 128)
    gex[tid] = __expf(gamma[tid * Hd + j] - gstat[0]) * (1.f / gstat[1]);
  __syncthreads();

  float psum[4];
#pragma unroll
  for (int bt = 0; bt < 4; ++bt) {
    const int b = bt * 16 + l15;
    const float M = Mb[b];
    float sum = 0.f;
#pragma unroll
    for (int r = 0; r < 4; ++r)
      sum += gex[ibase + r] * __expf(val[bt][r] - M);
    sum += __shfl_xor(sum, 16, 64);
    sum += __shfl_xor(sum, 32, 64);
    psum[bt] = sum;
  }
  if (lane < 16) {
#pragma unroll
    for (int bt = 0; bt < 4; ++bt) wred[w][bt * 16 + lane] = psum[bt];
  }
  __syncthreads();
  if (tid < 64) {
    float sm = wred[0][tid] + wred[1][tid] + wred[2][tid] + wred[3][tid];
    gpart[bid * Bd + tid] = sm;
  }
  grid_barrier(bar);
  if (bid == 0 && tid < 64) {
    float sum = 0.f;
    for (int q = 0; q < NBLK; ++q) sum += gpart[q * Bd + tid];
    out[(size_t)Sd * HHBc + tid] = __logf(sum + EPSF) + Mb[tid];
  }
}

extern "C" void kernel_launch(void* const* d_in, const int* in_sizes, int n_in,
                              void* d_out, int out_size, void* d_ws, size_t ws_size,
                              hipStream_t stream) {
  const int* ids = (const int*)d_in[0];
  const float* alpha = (const float*)d_in[1];
  const float* beta = (const float*)d_in[2];
  const float* gamma = (const float*)d_in[3];
  float* out = (float*)d_out;
  float* ws = (float*)d_ws;

  // reset the grid-barrier state (captured as a graph node; re-runs each replay)
  hipMemsetAsync(ws, 0, 64, stream);
  hipLaunchKernelGGL(sohmm_persistent, dim3(NBLK), dim3(256), 0, stream,
                     ids, alpha, beta, gamma, out, ws);
}